// Round 13
// baseline (117.920 us; speedup 1.0000x reference)
//
#include <hip/hip_runtime.h>

// CMDNet_58274116272706 — B=16384, NR=64, NT=32, M=4, NITER=64.
// R13: SPLIT KERNEL (R11 structure) with allocation pinned via
// waves_per_eu(6,6). R11 post-mortem: descent hit 83% VALUBusy (TLP works!)
// but the (6,8) attr let the allocator shrink to 32 VGPRs chasing max=8 ->
// remat bloat (97µs). (6,6): min=6 mandates <=85 regs, max=6 removes any
// incentive to allocate below 85 -> the ~50-reg ILP=1 loop fits cleanly at
// 6 waves/SIMD (grid supports 8/SIMD; regs cap realized occupancy at 6).
//   Kernel A (gram): Gram via f16 MFMA + yH -> d_ws (hh f16 pairs in the
//                    per-lane read layout, coalesced both directions).
//   Kernel B (descent): ILP=1, 2 batches/wave, no MFMA, dot seeded -yH.
// Fallback if ws too small: R9 monolithic (94.5µs proven).
// Math lineage: softmax exp2-domain WITH max-sub (R5 NaN lesson); absmax
// 0.015625 across R6/R9/R11/R12.

#define NRr 64
#define NTt 32
#define NITER 64
#define B_TOTAL 16384

#define HH_WS_BYTES ((size_t)B_TOTAL * 512 * 4)          // 32 MiB
#define YH_WS_OFF   HH_WS_BYTES
#define YH_WS_BYTES ((size_t)B_TOTAL * NTt * 4)          // 2 MiB
#define WS_NEEDED   (HH_WS_BYTES + YH_WS_BYTES)

using f16x8  = __attribute__((ext_vector_type(8))) _Float16;
using h16x2  = __attribute__((ext_vector_type(2))) _Float16;
using f32x16 = __attribute__((ext_vector_type(16))) float;

static __device__ __forceinline__ uint32_t pk16(float a, float b) {
    union { _Float16 h[2]; uint32_t u; } x;
    x.h[0] = (_Float16)a; x.h[1] = (_Float16)b;   // RNE
    return x.u;
}

static __device__ __forceinline__ float fdot2u(uint32_t a, uint32_t b, float c) {
    union { uint32_t u; h16x2 h; } x, y;
    x.u = a; y.u = b;
#if __has_builtin(__builtin_amdgcn_fdot2)
    return __builtin_amdgcn_fdot2(x.h, y.h, c, false);
#else
    return c + (float)x.h[0] * (float)y.h[0] + (float)x.h[1] * (float)y.h[1];
#endif
}

static __device__ __forceinline__ float exp2fast(float x) {
#if __has_builtin(__builtin_amdgcn_exp2f)
    return __builtin_amdgcn_exp2f(x);
#else
    return exp2f(x);
#endif
}

static __device__ __forceinline__ float rdlane(float v, int lane) {
    return __builtin_bit_cast(float,
        __builtin_amdgcn_readlane(__builtin_bit_cast(int, v), lane));
}

static __device__ __forceinline__ float rfl(float v) {
    return __builtin_bit_cast(float,
        __builtin_amdgcn_readfirstlane(__builtin_bit_cast(int, v)));
}

// Gram fragment + y-partial for one batch. ap[2g+c2] = f16 pair of
// HH rows (8g+4hi+2c2, +1) at column j; ypart = y·H over this lane's ks.
static __device__ __forceinline__ void gram_one(
    const float* __restrict__ hp, const float* __restrict__ ypt,
    const int hi, uint32_t ap[8], float& ypart_out)
{
    f32x16 acc = {};
    float  ypart = 0.f;
#pragma unroll
    for (int kc = 0; kc < 4; ++kc) {
        const int kb = kc * 16 + hi * 8;      // this lane's 8 k values
        float h[8];
#pragma unroll
        for (int e = 0; e < 8; ++e) h[e] = hp[(size_t)(kb + e) * NTt];
        const float4 ya = *(const float4*)(ypt + kb);
        const float4 yb = *(const float4*)(ypt + kb + 4);
        ypart += h[0]*ya.x + h[1]*ya.y + h[2]*ya.z + h[3]*ya.w
               + h[4]*yb.x + h[5]*yb.y + h[6]*yb.z + h[7]*yb.w;
        f16x8 fa;
#pragma unroll
        for (int e = 0; e < 8; ++e) fa[e] = (_Float16)h[e];
        // A-frag == B-frag: Gram product is k-permutation-insensitive.
        acc = __builtin_amdgcn_mfma_f32_32x32x16_f16(fa, fa, acc, 0, 0, 0);
    }
    // C layout: col=lane&31, row=(r&3)+8*(r>>2)+4*hi. Pack row pairs.
#pragma unroll
    for (int g = 0; g < 4; ++g) {
        ap[2*g+0] = pk16(acc[4*g+0], acc[4*g+1]);
        ap[2*g+1] = pk16(acc[4*g+2], acc[4*g+3]);
    }
    ypart_out = ypart;
}

// Exchange stripes with lane^32 and assemble full 32-row column (16 pairs).
static __device__ __forceinline__ void exch_hh(
    const uint32_t apx[8], const uint32_t apy[8], const int hi, uint32_t hh[16])
{
#pragma unroll
    for (int p = 0; p < 8; ++p) {
        const uint32_t snd = hi ? apx[p] : apy[p];        // partner's batch
        const uint32_t rcv = (uint32_t)__shfl_xor((int)snd, 32, 64);
        const uint32_t own = hi ? apy[p] : apx[p];
        const int g = p >> 1, cc = p & 1;
        hh[4*g + cc]     = hi ? rcv : own;    // stripe 0 (rows 8g+2cc,+1)
        hh[4*g + 2 + cc] = hi ? own : rcv;    // stripe 1 (rows 8g+4+2cc,+1)
    }
}

// ============================ Kernel A: Gram ===============================
__global__ __launch_bounds__(256)
__attribute__((amdgpu_waves_per_eu(6, 6)))
void cmdnet_gram(
    const float* __restrict__ yt, const float* __restrict__ Ht,
    uint4* __restrict__ wsHH, float* __restrict__ wsYH)
{
    const int tid = threadIdx.x;
    const int w   = tid >> 6;
    const int l   = tid & 63;
    const int j   = l & 31;
    const int hi  = l >> 5;
    const int c0  = (blockIdx.x * 4 + w) * 2;

    const size_t hstride = (size_t)NRr * NTt;

    uint32_t apx[8], apy[8];
    float ypx, ypy;
    gram_one(Ht + (size_t)(c0    ) * hstride + j, yt + (size_t)(c0    ) * NRr, hi, apx, ypx);
    gram_one(Ht + (size_t)(c0 + 1) * hstride + j, yt + (size_t)(c0 + 1) * NRr, hi, apy, ypy);

    uint32_t hh[16];
    exch_hh(apx, apy, hi, hh);
    const float snd = hi ? ypx : ypy;
    const float rcv = __shfl_xor(snd, 32, 64);
    const float yH_v = (hi ? ypy : ypx) + rcv;

    const int bmy = c0 + hi;
#pragma unroll
    for (int qg = 0; qg < 4; ++qg) {
        uint4 v; v.x = hh[4*qg+0]; v.y = hh[4*qg+1];
                 v.z = hh[4*qg+2]; v.w = hh[4*qg+3];
        wsHH[(size_t)bmy * 128 + qg * 32 + j] = v;
    }
    wsYH[(size_t)bmy * NTt + j] = yH_v;
}

// =========================== Kernel B: descent =============================
// ILP=1: 2 batches/wave, lane (j,hi) owns batch c0+hi. Grid 2048 blocks ->
// 8 waves/SIMD available; (6,6) pins regs at <=85 so 6 realize, no remat.
__global__ __launch_bounds__(256)
__attribute__((amdgpu_waves_per_eu(6, 6)))
void cmdnet_descent(
    const uint4* __restrict__ wsHH, const float* __restrict__ wsYH,
    const float* __restrict__ sig0, const float* __restrict__ mm,
    const float* __restrict__ alpha, const float* __restrict__ taui,
    const float* __restrict__ delta, float* __restrict__ out)
{
    __shared__ __align__(16) _Float16 xtsh[4][2][32];  // [wave][hi][nt]

    const int tid = threadIdx.x;
    const int w   = tid >> 6;
    const int l   = tid & 63;
    const int j   = l & 31;
    const int hi  = l >> 5;
    const int c0  = (blockIdx.x * 4 + w) * 2;
    const int bmy = c0 + hi;

    const float vta = fabsf(taui[l]);
    const float vd  = delta[l];

    uint32_t hh[16];
#pragma unroll
    for (int qg = 0; qg < 4; ++qg) {
        const uint4 v = wsHH[(size_t)bmy * 128 + qg * 32 + j];
        hh[4*qg+0] = v.x; hh[4*qg+1] = v.y; hh[4*qg+2] = v.z; hh[4*qg+3] = v.w;
    }
    const float yH_v = wsYH[(size_t)bmy * NTt + j];

    const float sgv  = sig0[bmy];
    const float sig2 = sgv * sgv;

    const float4 mv = *(const float4*)mm;
    const float4 av = *(const float4*)alpha;
    const float m0 = rfl(mv.x), m1 = rfl(mv.y), m2 = rfl(mv.z), m3 = rfl(mv.w);
    const float la0 = rfl(__log2f(av.x)), la1 = rfl(__log2f(av.y));
    const float la2 = rfl(__log2f(av.z)), la3 = rfl(__log2f(av.w));

    const float L2E  = 1.4426950408889634f;
    const float NL2E = -1.4426950408889634f;

    _Float16*    xwp = &xtsh[w][hi][j];
    const uint4* xrp = (const uint4*)&xtsh[w][hi][0];

    float G0 = 0.f, G1 = 0.f, G2 = 0.f, G3 = 0.f;

    for (int it = 0; it < NITER; ++it) {
        const float ta  = rdlane(vta, it);
        const float d   = rdlane(vd,  it);
        const float sc  = (it == 0) ? 1.0f : ta;  // first layer: scale 1
        const float scL = sc * L2E;
        const float tad = ta * d;
        const float c1  = d * sig2;
        const float ls0 = la0 * sc, ls1 = la1 * sc,
                    ls2 = la2 * sc, ls3 = la3 * sc;

        // softmax over M=4, exp2 domain, WITH max-subtraction
        const float s0 = fmaf(G0, scL, ls0), s1 = fmaf(G1, scL, ls1);
        const float s2 = fmaf(G2, scL, ls2), s3 = fmaf(G3, scL, ls3);
        const float mx = fmaxf(fmaxf(fmaxf(s0, s1), s2), s3);   // v_max3
        const float e0 = exp2fast(s0 - mx), e1 = exp2fast(s1 - mx);
        const float e2 = exp2fast(s2 - mx), e3 = exp2fast(s3 - mx);
        const float Z  = (e0 + e1) + (e2 + e3);
        const float R  = __builtin_amdgcn_rcpf(Z);
        const float S  = fmaf(e0, m0, fmaf(e1, m1, fmaf(e2, m2, e3 * m3)));
        const float xt = S * R;

        // broadcast xt within half-wave (same-wave DS ops are in-order)
        *xwp = (_Float16)xt;
        asm volatile("" ::: "memory");

        // barrier exps overlap the LDS round-trip
        const float en0 = exp2fast(G0 * NL2E), en1 = exp2fast(G1 * NL2E);
        const float en2 = exp2fast(G2 * NL2E), en3 = exp2fast(G3 * NL2E);

        const uint4 a0 = xrp[0], a1 = xrp[1], a2 = xrp[2], a3 = xrp[3];
        asm volatile("" ::: "memory");

        // xHH - yH via v_dot2_f32_f16 — 4 chains of depth 4, seeded with -yH
        float p0 = fdot2u(hh[ 0], a0.x, -yH_v);
        float p1 = fdot2u(hh[ 1], a0.y, 0.f);
        float p2 = fdot2u(hh[ 2], a0.z, 0.f);
        float p3 = fdot2u(hh[ 3], a0.w, 0.f);
        p0 = fdot2u(hh[ 4], a1.x, p0); p1 = fdot2u(hh[ 5], a1.y, p1);
        p2 = fdot2u(hh[ 6], a1.z, p2); p3 = fdot2u(hh[ 7], a1.w, p3);
        p0 = fdot2u(hh[ 8], a2.x, p0); p1 = fdot2u(hh[ 9], a2.y, p1);
        p2 = fdot2u(hh[10], a2.z, p2); p3 = fdot2u(hh[11], a2.w, p3);
        p0 = fdot2u(hh[12], a3.x, p0); p1 = fdot2u(hh[13], a3.y, p1);
        p2 = fdot2u(hh[14], a3.z, p2); p3 = fdot2u(hh[15], a3.w, p3);

        const float qd = (p0 + p1) + (p2 + p3);   // xHH - yH
        const float tq = tad * qd * R;            // folds ta, delta, 1/Z

        // G' = (G - c1) + c1*exp(-G) - tq * e_i * (m_i - xt)
        G0 = fmaf(-tq, e0 * (m0 - xt), fmaf(c1, en0, G0 - c1));
        G1 = fmaf(-tq, e1 * (m1 - xt), fmaf(c1, en1, G1 - c1));
        G2 = fmaf(-tq, e2 * (m2 - xt), fmaf(c1, en2, G2 - c1));
        G3 = fmaf(-tq, e3 * (m3 - xt), fmaf(c1, en3, G3 - c1));
    }

    // Final layer: softmax + soft symbol, store
    const float tap = fabsf(taui[NITER]);
    {
        const float w0 = fmaf(G0, L2E, la0) * tap;
        const float w1 = fmaf(G1, L2E, la1) * tap;
        const float w2 = fmaf(G2, L2E, la2) * tap;
        const float w3 = fmaf(G3, L2E, la3) * tap;
        const float mx = fmaxf(fmaxf(fmaxf(w0, w1), w2), w3);
        const float e0 = exp2fast(w0 - mx), e1 = exp2fast(w1 - mx);
        const float e2 = exp2fast(w2 - mx), e3 = exp2fast(w3 - mx);
        const float Z  = (e0 + e1) + (e2 + e3);
        const float R  = __builtin_amdgcn_rcpf(Z);
        const float f0 = e0 * R, f1 = e1 * R, f2 = e2 * R, f3 = e3 * R;
        const float xt = fmaf(f0, m0, fmaf(f1, m1, fmaf(f2, m2, f3 * m3)));

        float4 f4; f4.x = f0; f4.y = f1; f4.z = f2; f4.w = f3;
        *(float4*)(out + ((size_t)bmy * NTt + j) * 4) = f4;
        out[(size_t)B_TOTAL * NTt * 4 + (size_t)bmy * NTt + j] = xt;
    }
}

// ================= Fallback: R9 monolithic (94.5 µs, proven) ==============
__global__ __launch_bounds__(256)
__attribute__((amdgpu_waves_per_eu(4, 4)))
void cmdnet_mono(
    const float* __restrict__ yt, const float* __restrict__ Ht,
    const float* __restrict__ sig0, const float* __restrict__ mm,
    const float* __restrict__ alpha, const float* __restrict__ taui,
    const float* __restrict__ delta, float* __restrict__ out)
{
    __shared__ __align__(16) _Float16 xtsh[4][4][32];

    const int tid = threadIdx.x;
    const int w   = tid >> 6;
    const int l   = tid & 63;
    const int j   = l & 31;
    const int hi  = l >> 5;
    const int c0  = (blockIdx.x * 4 + w) * 4;

    const float vta = fabsf(taui[l]);
    const float vd  = delta[l];
    const size_t hstride = (size_t)NRr * NTt;

    uint32_t hhA[16], hhB[16];
    float yHA_v, yHB_v;
    {
        uint32_t apx[8], apy[8]; float ypx, ypy;
        gram_one(Ht + (size_t)(c0    ) * hstride + j, yt + (size_t)(c0    ) * NRr, hi, apx, ypx);
        gram_one(Ht + (size_t)(c0 + 2) * hstride + j, yt + (size_t)(c0 + 2) * NRr, hi, apy, ypy);
        exch_hh(apx, apy, hi, hhA);
        const float snd = hi ? ypx : ypy;
        const float rcv = __shfl_xor(snd, 32, 64);
        yHA_v = (hi ? ypy : ypx) + rcv;
    }
    {
        uint32_t apx[8], apy[8]; float ypx, ypy;
        gram_one(Ht + (size_t)(c0 + 1) * hstride + j, yt + (size_t)(c0 + 1) * NRr, hi, apx, ypx);
        gram_one(Ht + (size_t)(c0 + 3) * hstride + j, yt + (size_t)(c0 + 3) * NRr, hi, apy, ypy);
        exch_hh(apx, apy, hi, hhB);
        const float snd = hi ? ypx : ypy;
        const float rcv = __shfl_xor(snd, 32, 64);
        yHB_v = (hi ? ypy : ypx) + rcv;
    }

    const int bA = c0 + 2*hi;
    const int bB = bA + 1;
    const float sgA = sig0[bA], sgB = sig0[bB];
    const float sig2A = sgA * sgA, sig2B = sgB * sgB;

    const float4 mv = *(const float4*)mm;
    const float4 av = *(const float4*)alpha;
    const float m0 = rfl(mv.x), m1 = rfl(mv.y), m2 = rfl(mv.z), m3 = rfl(mv.w);
    const float la0 = rfl(__log2f(av.x)), la1 = rfl(__log2f(av.y));
    const float la2 = rfl(__log2f(av.z)), la3 = rfl(__log2f(av.w));

    const float L2E  = 1.4426950408889634f;
    const float NL2E = -1.4426950408889634f;

    _Float16* xwA = &xtsh[w][2*hi][j];
    _Float16* xwB = &xtsh[w][2*hi+1][j];
    const uint4* xr = (const uint4*)&xtsh[w][2*hi][0];

    float GA0 = 0.f, GA1 = 0.f, GA2 = 0.f, GA3 = 0.f;
    float GB0 = 0.f, GB1 = 0.f, GB2 = 0.f, GB3 = 0.f;

#pragma unroll 2
    for (int it = 0; it < NITER; ++it) {
        const float ta  = rdlane(vta, it);
        const float d   = rdlane(vd,  it);
        const float sc  = (it == 0) ? 1.0f : ta;
        const float scL = sc * L2E;
        const float tad = ta * d;
        const float c1A = d * sig2A, c1B = d * sig2B;
        const float ls0 = la0 * sc, ls1 = la1 * sc,
                    ls2 = la2 * sc, ls3 = la3 * sc;

        const float sA0 = fmaf(GA0, scL, ls0), sA1 = fmaf(GA1, scL, ls1);
        const float sA2 = fmaf(GA2, scL, ls2), sA3 = fmaf(GA3, scL, ls3);
        const float sB0 = fmaf(GB0, scL, ls0), sB1 = fmaf(GB1, scL, ls1);
        const float sB2 = fmaf(GB2, scL, ls2), sB3 = fmaf(GB3, scL, ls3);
        const float mxA = fmaxf(fmaxf(fmaxf(sA0, sA1), sA2), sA3);
        const float mxB = fmaxf(fmaxf(fmaxf(sB0, sB1), sB2), sB3);
        const float eA0 = exp2fast(sA0 - mxA), eA1 = exp2fast(sA1 - mxA);
        const float eA2 = exp2fast(sA2 - mxA), eA3 = exp2fast(sA3 - mxA);
        const float eB0 = exp2fast(sB0 - mxB), eB1 = exp2fast(sB1 - mxB);
        const float eB2 = exp2fast(sB2 - mxB), eB3 = exp2fast(sB3 - mxB);
        const float ZA = (eA0 + eA1) + (eA2 + eA3);
        const float ZB = (eB0 + eB1) + (eB2 + eB3);
        const float RA = __builtin_amdgcn_rcpf(ZA);
        const float RB = __builtin_amdgcn_rcpf(ZB);
        const float SA = fmaf(eA0, m0, fmaf(eA1, m1, fmaf(eA2, m2, eA3 * m3)));
        const float SB = fmaf(eB0, m0, fmaf(eB1, m1, fmaf(eB2, m2, eB3 * m3)));
        const float xtA = SA * RA;
        const float xtB = SB * RB;

        *xwA = (_Float16)xtA;
        *xwB = (_Float16)xtB;
        asm volatile("" ::: "memory");

        const float enA0 = exp2fast(GA0 * NL2E), enA1 = exp2fast(GA1 * NL2E);
        const float enA2 = exp2fast(GA2 * NL2E), enA3 = exp2fast(GA3 * NL2E);
        const float enB0 = exp2fast(GB0 * NL2E), enB1 = exp2fast(GB1 * NL2E);
        const float enB2 = exp2fast(GB2 * NL2E), enB3 = exp2fast(GB3 * NL2E);

        float pA0 = 0.f, pA1 = 0.f, pB0 = 0.f, pB1 = 0.f;
        {
            const uint4 a0 = xr[0], a1 = xr[1];
            const uint4 b0 = xr[4], b1 = xr[5];
            pA0 = fdot2u(hhA[ 0], a0.x, pA0); pA1 = fdot2u(hhA[ 1], a0.y, pA1);
            pB0 = fdot2u(hhB[ 0], b0.x, pB0); pB1 = fdot2u(hhB[ 1], b0.y, pB1);
            pA0 = fdot2u(hhA[ 2], a0.z, pA0); pA1 = fdot2u(hhA[ 3], a0.w, pA1);
            pB0 = fdot2u(hhB[ 2], b0.z, pB0); pB1 = fdot2u(hhB[ 3], b0.w, pB1);
            pA0 = fdot2u(hhA[ 4], a1.x, pA0); pA1 = fdot2u(hhA[ 5], a1.y, pA1);
            pB0 = fdot2u(hhB[ 4], b1.x, pB0); pB1 = fdot2u(hhB[ 5], b1.y, pB1);
            pA0 = fdot2u(hhA[ 6], a1.z, pA0); pA1 = fdot2u(hhA[ 7], a1.w, pA1);
            pB0 = fdot2u(hhB[ 6], b1.z, pB0); pB1 = fdot2u(hhB[ 7], b1.w, pB1);
        }
        {
            const uint4 a2 = xr[2], a3 = xr[3];
            const uint4 b2 = xr[6], b3 = xr[7];
            pA0 = fdot2u(hhA[ 8], a2.x, pA0); pA1 = fdot2u(hhA[ 9], a2.y, pA1);
            pB0 = fdot2u(hhB[ 8], b2.x, pB0); pB1 = fdot2u(hhB[ 9], b2.y, pB1);
            pA0 = fdot2u(hhA[10], a2.z, pA0); pA1 = fdot2u(hhA[11], a2.w, pA1);
            pB0 = fdot2u(hhB[10], b2.z, pB0); pB1 = fdot2u(hhB[11], b2.w, pB1);
            pA0 = fdot2u(hhA[12], a3.x, pA0); pA1 = fdot2u(hhA[13], a3.y, pA1);
            pB0 = fdot2u(hhB[12], b3.x, pB0); pB1 = fdot2u(hhB[13], b3.y, pB1);
            pA0 = fdot2u(hhA[14], a3.z, pA0); pA1 = fdot2u(hhA[15], a3.w, pA1);
            pB0 = fdot2u(hhB[14], b3.z, pB0); pB1 = fdot2u(hhB[15], b3.w, pB1);
        }
        asm volatile("" ::: "memory");

        const float qdA = (pA0 + pA1) - yHA_v;
        const float qdB = (pB0 + pB1) - yHB_v;
        const float tqA = tad * qdA * RA;
        const float tqB = tad * qdB * RB;

        GA0 = fmaf(-tqA, eA0 * (m0 - xtA), fmaf(c1A, enA0, GA0 - c1A));
        GA1 = fmaf(-tqA, eA1 * (m1 - xtA), fmaf(c1A, enA1, GA1 - c1A));
        GA2 = fmaf(-tqA, eA2 * (m2 - xtA), fmaf(c1A, enA2, GA2 - c1A));
        GA3 = fmaf(-tqA, eA3 * (m3 - xtA), fmaf(c1A, enA3, GA3 - c1A));
        GB0 = fmaf(-tqB, eB0 * (m0 - xtB), fmaf(c1B, enB0, GB0 - c1B));
        GB1 = fmaf(-tqB, eB1 * (m1 - xtB), fmaf(c1B, enB1, GB1 - c1B));
        GB2 = fmaf(-tqB, eB2 * (m2 - xtB), fmaf(c1B, enB2, GB2 - c1B));
        GB3 = fmaf(-tqB, eB3 * (m3 - xtB), fmaf(c1B, enB3, GB3 - c1B));
    }

    const float tap = fabsf(taui[NITER]);
#pragma unroll
    for (int s = 0; s < 2; ++s) {
        const float G0 = s ? GB0 : GA0, G1 = s ? GB1 : GA1;
        const float G2 = s ? GB2 : GA2, G3 = s ? GB3 : GA3;
        const int   bm = s ? bB : bA;
        const float w0 = fmaf(G0, L2E, la0) * tap;
        const float w1 = fmaf(G1, L2E, la1) * tap;
        const float w2 = fmaf(G2, L2E, la2) * tap;
        const float w3 = fmaf(G3, L2E, la3) * tap;
        const float mx = fmaxf(fmaxf(fmaxf(w0, w1), w2), w3);
        const float e0 = exp2fast(w0 - mx), e1 = exp2fast(w1 - mx);
        const float e2 = exp2fast(w2 - mx), e3 = exp2fast(w3 - mx);
        const float Z  = (e0 + e1) + (e2 + e3);
        const float R  = __builtin_amdgcn_rcpf(Z);
        const float f0 = e0 * R, f1 = e1 * R, f2 = e2 * R, f3 = e3 * R;
        const float xt = fmaf(f0, m0, fmaf(f1, m1, fmaf(f2, m2, f3 * m3)));

        float4 f4; f4.x = f0; f4.y = f1; f4.z = f2; f4.w = f3;
        *(float4*)(out + ((size_t)bm * NTt + j) * 4) = f4;
        out[(size_t)B_TOTAL * NTt * 4 + (size_t)bm * NTt + j] = xt;
    }
}

extern "C" void kernel_launch(void* const* d_in, const int* in_sizes, int n_in,
                              void* d_out, int out_size, void* d_ws, size_t ws_size,
                              hipStream_t stream) {
    const float* yt    = (const float*)d_in[0];
    const float* Ht    = (const float*)d_in[1];
    const float* sig0  = (const float*)d_in[2];
    const float* mm    = (const float*)d_in[3];
    const float* alpha = (const float*)d_in[4];
    const float* taui  = (const float*)d_in[5];
    const float* delta = (const float*)d_in[6];
    float* out = (float*)d_out;

    if (ws_size >= WS_NEEDED && d_ws != nullptr) {
        uint4* wsHH = (uint4*)d_ws;
        float* wsYH = (float*)((char*)d_ws + YH_WS_OFF);
        cmdnet_gram<<<B_TOTAL / 8, 256, 0, stream>>>(yt, Ht, wsHH, wsYH);
        cmdnet_descent<<<B_TOTAL / 8, 256, 0, stream>>>(wsHH, wsYH, sig0, mm,
                                                        alpha, taui, delta, out);
    } else {
        cmdnet_mono<<<B_TOTAL / 16, 256, 0, stream>>>(yt, Ht, sig0, mm, alpha,
                                                      taui, delta, out);
    }
}

// Round 14
// 94.436 us; speedup vs baseline: 1.2487x; 1.2487x over previous
//
#include <hip/hip_runtime.h>

// CMDNet_58274116272706 — B=16384, NR=64, NT=32, M=4, NITER=64.
// FINAL (R14 = R9 verbatim, session best 94.5µs): monolithic kernel.
// Phase 1: HH = Ht^T Ht per batch via f16 MFMA (Gram trick: A-frag == B-frag),
//          yH = y^T Ht in f32 VALU. Two passes of 2 batches each -> VGPR 60,
//          zero spills (WRITE_SIZE exactly 10240 KB).
// Phase 2: 64 gradient steps. 4 batches per wave, 2 per lane (ILP=2):
//          lane (hi,j) owns column j of batches c0+2*hi and c0+2*hi+1.
//          HH columns as f16 pairs in VGPRs, matvec via v_dot2_f32_f16,
//          xt broadcast through f16 LDS, taui/delta via v_readlane,
//          softmax exp2-domain WITH max-subtraction (R5: removing it NaNs),
//          unroll 2 + windowed LDS reads + max3-shaped reductions.
// Session ledger (13 rounds): occupancy moves (R2/R4/R8/R11/R13) spill or
// remat; packed f32 (R7) spills; MFMA matvec (R10) adds latency; wave
// desync (R12) falsified. ILP=2 @ 4 waves/SIMD, waves_per_eu(4,4) is the
// operating point; ~64% VALUBusy is the realized interleave at the
// grid-capped occupancy (4096 waves fixed by B/ILP).

#define NRr 64
#define NTt 32
#define NITER 64
#define B_TOTAL 16384

using f16x8  = __attribute__((ext_vector_type(8))) _Float16;
using h16x2  = __attribute__((ext_vector_type(2))) _Float16;
using f32x16 = __attribute__((ext_vector_type(16))) float;

static __device__ __forceinline__ uint32_t pk16(float a, float b) {
    union { _Float16 h[2]; uint32_t u; } x;
    x.h[0] = (_Float16)a; x.h[1] = (_Float16)b;   // RNE
    return x.u;
}

static __device__ __forceinline__ float fdot2u(uint32_t a, uint32_t b, float c) {
    union { uint32_t u; h16x2 h; } x, y;
    x.u = a; y.u = b;
#if __has_builtin(__builtin_amdgcn_fdot2)
    return __builtin_amdgcn_fdot2(x.h, y.h, c, false);
#else
    return c + (float)x.h[0] * (float)y.h[0] + (float)x.h[1] * (float)y.h[1];
#endif
}

static __device__ __forceinline__ float exp2fast(float x) {
#if __has_builtin(__builtin_amdgcn_exp2f)
    return __builtin_amdgcn_exp2f(x);
#else
    return exp2f(x);
#endif
}

static __device__ __forceinline__ float rdlane(float v, int lane) {
    return __builtin_bit_cast(float,
        __builtin_amdgcn_readlane(__builtin_bit_cast(int, v), lane));
}

static __device__ __forceinline__ float rfl(float v) {
    return __builtin_bit_cast(float,
        __builtin_amdgcn_readfirstlane(__builtin_bit_cast(int, v)));
}

// Gram fragment + y-partial for one batch. ap[8] = f16-packed row-pair
// stripes of column j (rows 8g+4hi+2cc, +1), ypart = y·H over this lane's ks.
static __device__ __forceinline__ void gram_one(
    const float* __restrict__ hp, const float* __restrict__ ypt,
    const int hi, uint32_t ap[8], float& ypart_out)
{
    f32x16 acc = {};
    float  ypart = 0.f;
#pragma unroll
    for (int kc = 0; kc < 4; ++kc) {
        const int kb = kc * 16 + hi * 8;      // this lane's 8 k values
        float h[8];
#pragma unroll
        for (int e = 0; e < 8; ++e) h[e] = hp[(size_t)(kb + e) * NTt];
        const float4 ya = *(const float4*)(ypt + kb);
        const float4 yb = *(const float4*)(ypt + kb + 4);
        ypart += h[0]*ya.x + h[1]*ya.y + h[2]*ya.z + h[3]*ya.w
               + h[4]*yb.x + h[5]*yb.y + h[6]*yb.z + h[7]*yb.w;
        f16x8 fa;
#pragma unroll
        for (int e = 0; e < 8; ++e) fa[e] = (_Float16)h[e];
        // A-frag == B-frag: Gram product is k-permutation-insensitive.
        acc = __builtin_amdgcn_mfma_f32_32x32x16_f16(fa, fa, acc, 0, 0, 0);
    }
    // C layout: col=lane&31, row=(r&3)+8*(r>>2)+4*hi. Pack row pairs.
#pragma unroll
    for (int g = 0; g < 4; ++g) {
        ap[2*g+0] = pk16(acc[4*g+0], acc[4*g+1]);
        ap[2*g+1] = pk16(acc[4*g+2], acc[4*g+3]);
    }
    ypart_out = ypart;
}

// Exchange stripes with lane^32 and assemble full 32-row column (16 pairs).
static __device__ __forceinline__ void exch_hh(
    const uint32_t apx[8], const uint32_t apy[8], const int hi, uint32_t hh[16])
{
#pragma unroll
    for (int p = 0; p < 8; ++p) {
        const uint32_t snd = hi ? apx[p] : apy[p];        // partner's batch
        const uint32_t rcv = (uint32_t)__shfl_xor((int)snd, 32, 64);
        const uint32_t own = hi ? apy[p] : apx[p];
        const int g = p >> 1, cc = p & 1;
        hh[4*g + cc]     = hi ? rcv : own;    // stripe 0 (rows 8g+2cc,+1)
        hh[4*g + 2 + cc] = hi ? own : rcv;    // stripe 1 (rows 8g+4+2cc,+1)
    }
}

__global__ __launch_bounds__(256)
__attribute__((amdgpu_waves_per_eu(4, 4)))
void cmdnet_kernel(
    const float* __restrict__ yt,     // [B,64]
    const float* __restrict__ Ht,     // [B,64,32]
    const float* __restrict__ sig0,   // [B]
    const float* __restrict__ mm,     // [4]
    const float* __restrict__ alpha,  // [4]
    const float* __restrict__ taui,   // [65]
    const float* __restrict__ delta,  // [64]
    float* __restrict__ out)          // ft [B,32,4] then xt [B,32]
{
    __shared__ __align__(16) _Float16 xtsh[4][4][32];  // [wave][batch-slot][nt]

    const int tid = threadIdx.x;
    const int w   = tid >> 6;                 // wave in block
    const int l   = tid & 63;                 // lane
    const int j   = l & 31;                   // nt / matrix column
    const int hi  = l >> 5;                   // half-wave id
    const int c0  = (blockIdx.x * 4 + w) * 4; // wave's 4 batches

    // Per-iteration scalars parked in lane-indexed VGPRs (readlane in loop)
    const float vta = fabsf(taui[l]);         // |taui[it]| for it = lane
    const float vd  = delta[l];               // delta[it]

    const size_t hstride = (size_t)NRr * NTt;

    // ---------------- Phase 1: two passes of 2 batches each ----------------
    uint32_t hhA[16], hhB[16];
    float yHA_v, yHB_v;
    {   // pass 0: batches c0, c0+2 -> hhA (this lane keeps bA = c0+2*hi)
        uint32_t apx[8], apy[8];
        float ypx, ypy;
        gram_one(Ht + (size_t)(c0    ) * hstride + j, yt + (size_t)(c0    ) * NRr, hi, apx, ypx);
        gram_one(Ht + (size_t)(c0 + 2) * hstride + j, yt + (size_t)(c0 + 2) * NRr, hi, apy, ypy);
        exch_hh(apx, apy, hi, hhA);
        const float snd = hi ? ypx : ypy;
        const float rcv = __shfl_xor(snd, 32, 64);
        yHA_v = (hi ? ypy : ypx) + rcv;
    }
    {   // pass 1: batches c0+1, c0+3 -> hhB (this lane keeps bB = c0+2*hi+1)
        uint32_t apx[8], apy[8];
        float ypx, ypy;
        gram_one(Ht + (size_t)(c0 + 1) * hstride + j, yt + (size_t)(c0 + 1) * NRr, hi, apx, ypx);
        gram_one(Ht + (size_t)(c0 + 3) * hstride + j, yt + (size_t)(c0 + 3) * NRr, hi, apy, ypy);
        exch_hh(apx, apy, hi, hhB);
        const float snd = hi ? ypx : ypy;
        const float rcv = __shfl_xor(snd, 32, 64);
        yHB_v = (hi ? ypy : ypx) + rcv;
    }

    const int bA = c0 + 2*hi;
    const int bB = bA + 1;
    const float sgA = sig0[bA], sgB = sig0[bB];
    const float sig2A = sgA * sgA, sig2B = sgB * sgB;

    const float4 mv = *(const float4*)mm;
    const float4 av = *(const float4*)alpha;
    const float m0 = rfl(mv.x), m1 = rfl(mv.y), m2 = rfl(mv.z), m3 = rfl(mv.w);
    // exp2-domain softmax scores: (log2 a + G*log2e)*scale
    const float la0 = rfl(__log2f(av.x)), la1 = rfl(__log2f(av.y));
    const float la2 = rfl(__log2f(av.z)), la3 = rfl(__log2f(av.w));

    const float L2E  = 1.4426950408889634f;
    const float NL2E = -1.4426950408889634f;

    _Float16* xwA = &xtsh[w][2*hi][j];        // own batch slots
    _Float16* xwB = &xtsh[w][2*hi+1][j];
    const uint4* xr = (const uint4*)&xtsh[w][2*hi][0];  // [0..3]=A, [4..7]=B

    float GA0 = 0.f, GA1 = 0.f, GA2 = 0.f, GA3 = 0.f;
    float GB0 = 0.f, GB1 = 0.f, GB2 = 0.f, GB3 = 0.f;

    // ---------------- Phase 2: 64 descent steps ----------------------------
#pragma unroll 2
    for (int it = 0; it < NITER; ++it) {
        const float ta  = rdlane(vta, it);
        const float d   = rdlane(vd,  it);
        const float sc  = (it == 0) ? 1.0f : ta;  // first layer: scale 1
        const float scL = sc * L2E;
        const float tad = ta * d;
        const float c1A = d * sig2A, c1B = d * sig2B;
        const float ls0 = la0 * sc, ls1 = la1 * sc,
                    ls2 = la2 * sc, ls3 = la3 * sc;

        // softmax over M=4, exp2 domain, WITH max-subtraction
        const float sA0 = fmaf(GA0, scL, ls0), sA1 = fmaf(GA1, scL, ls1);
        const float sA2 = fmaf(GA2, scL, ls2), sA3 = fmaf(GA3, scL, ls3);
        const float sB0 = fmaf(GB0, scL, ls0), sB1 = fmaf(GB1, scL, ls1);
        const float sB2 = fmaf(GB2, scL, ls2), sB3 = fmaf(GB3, scL, ls3);
        const float mxA = fmaxf(fmaxf(fmaxf(sA0, sA1), sA2), sA3);  // v_max3
        const float mxB = fmaxf(fmaxf(fmaxf(sB0, sB1), sB2), sB3);
        const float eA0 = exp2fast(sA0 - mxA), eA1 = exp2fast(sA1 - mxA);
        const float eA2 = exp2fast(sA2 - mxA), eA3 = exp2fast(sA3 - mxA);
        const float eB0 = exp2fast(sB0 - mxB), eB1 = exp2fast(sB1 - mxB);
        const float eB2 = exp2fast(sB2 - mxB), eB3 = exp2fast(sB3 - mxB);
        const float ZA = (eA0 + eA1) + (eA2 + eA3);
        const float ZB = (eB0 + eB1) + (eB2 + eB3);
        const float RA = __builtin_amdgcn_rcpf(ZA);
        const float RB = __builtin_amdgcn_rcpf(ZB);
        const float SA = fmaf(eA0, m0, fmaf(eA1, m1, fmaf(eA2, m2, eA3 * m3)));
        const float SB = fmaf(eB0, m0, fmaf(eB1, m1, fmaf(eB2, m2, eB3 * m3)));
        const float xtA = SA * RA;
        const float xtB = SB * RB;

        // broadcast xt within half-wave (same-wave DS ops are in-order)
        *xwA = (_Float16)xtA;
        *xwB = (_Float16)xtB;
        asm volatile("" ::: "memory");

        // barrier exps are independent of the LDS round-trip — overlap it
        const float enA0 = exp2fast(GA0 * NL2E), enA1 = exp2fast(GA1 * NL2E);
        const float enA2 = exp2fast(GA2 * NL2E), enA3 = exp2fast(GA3 * NL2E);
        const float enB0 = exp2fast(GB0 * NL2E), enB1 = exp2fast(GB1 * NL2E);
        const float enB2 = exp2fast(GB2 * NL2E), enB3 = exp2fast(GB3 * NL2E);

        // windowed reads: first half, dot, then second half (peak regs -8)
        float pA0 = 0.f, pA1 = 0.f, pB0 = 0.f, pB1 = 0.f;
        {
            const uint4 a0 = xr[0], a1 = xr[1];
            const uint4 b0 = xr[4], b1 = xr[5];
            pA0 = fdot2u(hhA[ 0], a0.x, pA0); pA1 = fdot2u(hhA[ 1], a0.y, pA1);
            pB0 = fdot2u(hhB[ 0], b0.x, pB0); pB1 = fdot2u(hhB[ 1], b0.y, pB1);
            pA0 = fdot2u(hhA[ 2], a0.z, pA0); pA1 = fdot2u(hhA[ 3], a0.w, pA1);
            pB0 = fdot2u(hhB[ 2], b0.z, pB0); pB1 = fdot2u(hhB[ 3], b0.w, pB1);
            pA0 = fdot2u(hhA[ 4], a1.x, pA0); pA1 = fdot2u(hhA[ 5], a1.y, pA1);
            pB0 = fdot2u(hhB[ 4], b1.x, pB0); pB1 = fdot2u(hhB[ 5], b1.y, pB1);
            pA0 = fdot2u(hhA[ 6], a1.z, pA0); pA1 = fdot2u(hhA[ 7], a1.w, pA1);
            pB0 = fdot2u(hhB[ 6], b1.z, pB0); pB1 = fdot2u(hhB[ 7], b1.w, pB1);
        }
        {
            const uint4 a2 = xr[2], a3 = xr[3];
            const uint4 b2 = xr[6], b3 = xr[7];
            pA0 = fdot2u(hhA[ 8], a2.x, pA0); pA1 = fdot2u(hhA[ 9], a2.y, pA1);
            pB0 = fdot2u(hhB[ 8], b2.x, pB0); pB1 = fdot2u(hhB[ 9], b2.y, pB1);
            pA0 = fdot2u(hhA[10], a2.z, pA0); pA1 = fdot2u(hhA[11], a2.w, pA1);
            pB0 = fdot2u(hhB[10], b2.z, pB0); pB1 = fdot2u(hhB[11], b2.w, pB1);
            pA0 = fdot2u(hhA[12], a3.x, pA0); pA1 = fdot2u(hhA[13], a3.y, pA1);
            pB0 = fdot2u(hhB[12], b3.x, pB0); pB1 = fdot2u(hhB[13], b3.y, pB1);
            pA0 = fdot2u(hhA[14], a3.z, pA0); pA1 = fdot2u(hhA[15], a3.w, pA1);
            pB0 = fdot2u(hhB[14], b3.z, pB0); pB1 = fdot2u(hhB[15], b3.w, pB1);
        }
        asm volatile("" ::: "memory");

        const float qdA = (pA0 + pA1) - yHA_v;
        const float qdB = (pB0 + pB1) - yHB_v;
        const float tqA = tad * qdA * RA;         // folds ta, delta, 1/Z
        const float tqB = tad * qdB * RB;

        // G' = (G - c1) + c1*exp(-G) - tq * e_i * (m_i - xt)
        GA0 = fmaf(-tqA, eA0 * (m0 - xtA), fmaf(c1A, enA0, GA0 - c1A));
        GA1 = fmaf(-tqA, eA1 * (m1 - xtA), fmaf(c1A, enA1, GA1 - c1A));
        GA2 = fmaf(-tqA, eA2 * (m2 - xtA), fmaf(c1A, enA2, GA2 - c1A));
        GA3 = fmaf(-tqA, eA3 * (m3 - xtA), fmaf(c1A, enA3, GA3 - c1A));
        GB0 = fmaf(-tqB, eB0 * (m0 - xtB), fmaf(c1B, enB0, GB0 - c1B));
        GB1 = fmaf(-tqB, eB1 * (m1 - xtB), fmaf(c1B, enB1, GB1 - c1B));
        GB2 = fmaf(-tqB, eB2 * (m2 - xtB), fmaf(c1B, enB2, GB2 - c1B));
        GB3 = fmaf(-tqB, eB3 * (m3 - xtB), fmaf(c1B, enB3, GB3 - c1B));
    }

    // ---------------- Final layer: softmax + soft symbol, store ------------
    // scores: (ln a + G)*ta == (log2 a + G*log2e)*ta in exp2 domain
    const float tap = fabsf(taui[NITER]);
#pragma unroll
    for (int s = 0; s < 2; ++s) {
        const float G0 = s ? GB0 : GA0, G1 = s ? GB1 : GA1;
        const float G2 = s ? GB2 : GA2, G3 = s ? GB3 : GA3;
        const int   bm = s ? bB : bA;
        const float w0 = fmaf(G0, L2E, la0) * tap;
        const float w1 = fmaf(G1, L2E, la1) * tap;
        const float w2 = fmaf(G2, L2E, la2) * tap;
        const float w3 = fmaf(G3, L2E, la3) * tap;
        const float mx = fmaxf(fmaxf(fmaxf(w0, w1), w2), w3);
        const float e0 = exp2fast(w0 - mx), e1 = exp2fast(w1 - mx);
        const float e2 = exp2fast(w2 - mx), e3 = exp2fast(w3 - mx);
        const float Z  = (e0 + e1) + (e2 + e3);
        const float R  = __builtin_amdgcn_rcpf(Z);
        const float f0 = e0 * R, f1 = e1 * R, f2 = e2 * R, f3 = e3 * R;
        const float xt = fmaf(f0, m0, fmaf(f1, m1, fmaf(f2, m2, f3 * m3)));

        float4 f4; f4.x = f0; f4.y = f1; f4.z = f2; f4.w = f3;
        *(float4*)(out + ((size_t)bm * NTt + j) * 4) = f4;
        out[(size_t)B_TOTAL * NTt * 4 + (size_t)bm * NTt + j] = xt;
    }
}

extern "C" void kernel_launch(void* const* d_in, const int* in_sizes, int n_in,
                              void* d_out, int out_size, void* d_ws, size_t ws_size,
                              hipStream_t stream) {
    const float* yt    = (const float*)d_in[0];
    const float* Ht    = (const float*)d_in[1];
    const float* sig0  = (const float*)d_in[2];
    const float* mm    = (const float*)d_in[3];
    const float* alpha = (const float*)d_in[4];
    const float* taui  = (const float*)d_in[5];
    const float* delta = (const float*)d_in[6];
    float* out = (float*)d_out;

    const int blocks = B_TOTAL / 16;  // 16 batches per 256-thread block
    cmdnet_kernel<<<blocks, 256, 0, stream>>>(yt, Ht, sig0, mm, alpha, taui,
                                              delta, out);
}